// Round 8
// baseline (179.998 us; speedup 1.0000x reference)
//
#include <hip/hip_runtime.h>
#include <hip/hip_bf16.h>
#include <math.h>

#define BS 1024
#define D 128
#define NP 100000
#define PROWS 100096              // padded to multiple of 128 (96 zero rows)
#define CH 128                    // proxies per chunk/block
#define NCH (PROWS / CH)          // 782
#define NSLICE 16                 // rowsum slices (atomic contention / 16)
#define LOG2E 1.44269504088896340736f

typedef float f32x4 __attribute__((ext_vector_type(4)));
typedef __bf16 bf16x8 __attribute__((ext_vector_type(8)));
typedef unsigned short u16x8 __attribute__((ext_vector_type(8)));

#if defined(__has_builtin)
#if __has_builtin(__builtin_amdgcn_exp2f)
#define FAST_EXP2(x) __builtin_amdgcn_exp2f(x)
#endif
#endif
#ifndef FAST_EXP2
#define FAST_EXP2(x) exp2f(x)
#endif

static __device__ __forceinline__ unsigned short f2bf(float x) {
    unsigned int u = __float_as_uint(x);
    return (unsigned short)((u + 0x7fffu + ((u >> 16) & 1u)) >> 16);  // RNE
}

// ---------- kernel 1: batch -> bf16 A, d_pos; zero rowsum slices + counter -
__global__ __launch_bounds__(256) void prep_kernel(
    const float* __restrict__ batch, const float* __restrict__ proxies,
    const int* __restrict__ labels, unsigned short* __restrict__ A,
    float* __restrict__ d_pos, float* __restrict__ rowsum,
    unsigned int* __restrict__ counter)
{
    if (threadIdx.x < 128) rowsum[blockIdx.x * 128 + threadIdx.x] = 0.f;
    if (blockIdx.x == 0 && threadIdx.x == 0) *counter = 0u;

    int wave = threadIdx.x >> 6, lane = threadIdx.x & 63;
    int sub = lane >> 5, c = lane & 31;
    int row = blockIdx.x * 8 + wave * 2 + sub;   // 0..1023
    float4 v = *(const float4*)(batch + (size_t)row * D + c * 4);
    float ss = v.x*v.x + v.y*v.y + v.z*v.z + v.w*v.w;
    #pragma unroll
    for (int m = 1; m < 32; m <<= 1) ss += __shfl_xor(ss, m, 64);
    float sc = 3.0f / fmaxf(sqrtf(ss), 1e-12f);
    ushort4 pk;
    pk.x = f2bf(v.x*sc); pk.y = f2bf(v.y*sc);
    pk.z = f2bf(v.z*sc); pk.w = f2bf(v.w*sc);
    *(ushort4*)(A + (size_t)row * D + c * 4) = pk;
    // d_pos in fp32: 18 - 2*(b.p_label)
    int lab = labels[row];
    float4 p4 = *(const float4*)(proxies + (size_t)lab * D + c * 4);
    float ps = p4.x*p4.x + p4.y*p4.y + p4.z*p4.z + p4.w*p4.w;
    #pragma unroll
    for (int m = 1; m < 32; m <<= 1) ps += __shfl_xor(ps, m, 64);
    float psc = 3.0f / fmaxf(sqrtf(ps), 1e-12f);
    float dt = (v.x*sc)*(p4.x*psc) + (v.y*sc)*(p4.y*psc)
             + (v.z*sc)*(p4.z*psc) + (v.w*sc)*(p4.w*psc);
    #pragma unroll
    for (int m = 1; m < 32; m <<= 1) dt += __shfl_xor(dt, m, 64);
    if (c == 0) d_pos[row] = 18.0f - 2.0f * dt;
}

// ---------- kernel 2: fused proxy-norm + GEMM + exp row-sums + final ------
// 256 threads (4 waves), block = 128 proxies. Wave w: proxy-half ph=w&1
// (64 proxies, Af[4][4] = 64 VGPRs cached ONCE, pinned by barrier+clobber),
// row-half rh=w>>1 (512 batch rows, 32 groups of 16). Last finishing block
// performs the lse+mean reduction (device-scope counter).
__global__ __launch_bounds__(256, 3) void main_kernel(
    const float* __restrict__ proxies,
    const unsigned short* __restrict__ Abat,
    float* __restrict__ rowsum,          // [NSLICE][BS]
    const float* __restrict__ d_pos,
    float* __restrict__ out,
    unsigned int* __restrict__ counter)
{
    __shared__ unsigned short Plds[CH * D];   // 32 KB
    __shared__ unsigned int is_last;
    const int tid = threadIdx.x;
    const int lane = tid & 63;
    const int wave = tid >> 6, quad = lane >> 4, l15 = lane & 15;
    const int chunk = blockIdx.x;

    // ---- staging: r = tid>>1 (0..127), h = tid&1 (64 floats each) --------
    {
        int r = tid >> 1, h = tid & 1;
        int pidx = chunk * CH + r;
        const float* src = proxies + (size_t)pidx * D + h * 64;
        float ss = 0.f;
        if (pidx < NP) {
            #pragma unroll
            for (int j = 0; j < 16; ++j) {
                float4 v = *(const float4*)(src + j * 4);
                ss += v.x*v.x + v.y*v.y + v.z*v.z + v.w*v.w;
            }
        }
        ss += __shfl_xor(ss, 1, 64);             // combine the two halves
        float sc = 3.0f / fmaxf(sqrtf(ss), 1e-12f);
        #pragma unroll
        for (int j = 0; j < 8; ++j) {
            u16x8 w = (u16x8){0,0,0,0,0,0,0,0};
            if (pidx < NP) {
                float4 a = *(const float4*)(src + j * 8);      // L2 hit
                float4 b = *(const float4*)(src + j * 8 + 4);
                w[0] = f2bf(a.x*sc); w[1] = f2bf(a.y*sc);
                w[2] = f2bf(a.z*sc); w[3] = f2bf(a.w*sc);
                w[4] = f2bf(b.x*sc); w[5] = f2bf(b.y*sc);
                w[6] = f2bf(b.z*sc); w[7] = f2bf(b.w*sc);
            }
            int cl = h * 8 + j;                  // 16B chunk index in row
            *(u16x8*)((char*)Plds + r * 256 + ((cl ^ (r & 15)) << 4)) = w;
        }
    }
    __syncthreads();

    // ---- register-cache this wave's A-half: 64 VGPRs, loaded ONCE --------
    const int ph = wave & 1;        // proxy half: rows ph*64 .. +64
    const int rh = wave >> 1;       // batch-row half: rh*512 .. +512
    bf16x8 Af[4][4];
    #pragma unroll
    for (int m = 0; m < 4; ++m) {
        #pragma unroll
        for (int kk = 0; kk < 4; ++kk) {
            int prow = ph * 64 + m * 16 + l15;
            int cl = kk * 4 + quad;
            Af[m][kk] = *(const bf16x8*)((const char*)Plds + prow * 256 + ((cl ^ l15) << 4));
        }
    }
    __syncthreads();                              // Af loads cannot sink past
    *(unsigned int*)((char*)Plds + tid * 4) = 0u; // clobber: reload now unsound

    const float c1 = 2.0f * LOG2E, c0 = -18.0f * LOG2E;
    const int row0 = rh * 512;
    const unsigned short* ab = Abat + (size_t)(row0 + l15) * D + quad * 8;
    float* rs_base = rowsum + (size_t)(chunk & (NSLICE - 1)) * BS;

    bf16x8 Bf[2][4];
    #pragma unroll
    for (int kk = 0; kk < 4; ++kk) Bf[0][kk] = *(const bf16x8*)(ab + kk * 32);

    #pragma unroll 2
    for (int g = 0; g < 32; ++g) {
        if (g < 31) {   // prefetch next group's B-frags (L2-resident)
            #pragma unroll
            for (int kk = 0; kk < 4; ++kk)
                Bf[(g + 1) & 1][kk] = *(const bf16x8*)(ab + (size_t)(g + 1) * 16 * D + kk * 32);
        }
        f32x4 acc[4];
        #pragma unroll
        for (int m = 0; m < 4; ++m) acc[m] = (f32x4){0.f, 0.f, 0.f, 0.f};
        #pragma unroll
        for (int kk = 0; kk < 4; ++kk) {
            #pragma unroll
            for (int m = 0; m < 4; ++m)
                acc[m] = __builtin_amdgcn_mfma_f32_16x16x32_bf16(
                    Af[m][kk], Bf[g & 1][kk], acc[m], 0, 0, 0);
        }
        // epilogue: lane's batch col = row0+g*16+l15; 16 proxies in-lane
        float rs = 0.f;
        #pragma unroll
        for (int m = 0; m < 4; ++m) {
            float e0 = FAST_EXP2(fmaf(acc[m][0], c1, c0));
            float e1 = FAST_EXP2(fmaf(acc[m][1], c1, c0));
            float e2 = FAST_EXP2(fmaf(acc[m][2], c1, c0));
            float e3 = FAST_EXP2(fmaf(acc[m][3], c1, c0));
            rs += (e0 + e1) + (e2 + e3);
        }
        rs += __shfl_xor(rs, 16, 64);   // combine quads (proxy rows)
        rs += __shfl_xor(rs, 32, 64);
        if (quad == 0)
            atomicAdd(rs_base + row0 + g * 16 + l15, rs);
    }

    // ---- last-block-done: final lse + mean ------------------------------
    __syncthreads();
    if (tid == 0) {
        __threadfence();
        unsigned int old = __hip_atomic_fetch_add(counter, 1u,
                              __ATOMIC_ACQ_REL, __HIP_MEMORY_SCOPE_AGENT);
        is_last = (old == NCH - 1) ? 1u : 0u;
    }
    __syncthreads();
    if (is_last) {
        const float PADC = 96.0f * exp2f(-18.0f * LOG2E);  // zero-pad rows
        float accv = 0.f;
        #pragma unroll
        for (int i = 0; i < 4; ++i) {
            int row = tid * 4 + i;     // 0..1023
            float tot = 0.f;
            #pragma unroll
            for (int s = 0; s < NSLICE; ++s)
                tot += __hip_atomic_load(&rowsum[(size_t)s * BS + row],
                          __ATOMIC_RELAXED, __HIP_MEMORY_SCOPE_AGENT);
            float dp = d_pos[row];
            float neg = tot - expf(-dp) - PADC;            // drop own column
            accv += dp + logf(fmaxf(neg, 1e-37f));
        }
        #pragma unroll
        for (int m = 1; m < 64; m <<= 1) accv += __shfl_xor(accv, m, 64);
        float* shf = (float*)Plds;
        if ((tid & 63) == 0) shf[tid >> 6] = accv;
        __syncthreads();
        if (tid == 0)
            out[0] = (shf[0] + shf[1] + shf[2] + shf[3]) * (1.0f / 1024.0f);
    }
}

extern "C" void kernel_launch(void* const* d_in, const int* in_sizes, int n_in,
                              void* d_out, int out_size, void* d_ws, size_t ws_size,
                              hipStream_t stream) {
    const float* batch   = (const float*)d_in[0];
    const float* proxies = (const float*)d_in[1];
    const int*   labels  = (const int*)d_in[2];
    float* out = (float*)d_out;

    char* ws = (char*)d_ws;
    unsigned short* A    = (unsigned short*)ws;                  //   262,144 B
    float* d_pos         = (float*)(ws + 262144);                //     4,096 B
    float* rowsum        = (float*)(ws + 266240);                //    65,536 B
    unsigned int* counter= (unsigned int*)(ws + 331776);         //         4 B

    prep_kernel<<<128, 256, 0, stream>>>(batch, proxies, labels, A, d_pos,
                                         rowsum, counter);
    main_kernel<<<NCH, 256, 0, stream>>>(proxies, A, rowsum, d_pos, out, counter);
}